// Round 4
// baseline (116.653 us; speedup 1.0000x reference)
//
#include <hip/hip_runtime.h>

#define BATCH 131072
#define MUL 128
#define IRREP 9
#define ROWS_PER_BLOCK 4   // 1 row per wave, 4 waves per block
#define THREADS 256

__global__ __launch_bounds__(THREADS, 8) void symcon_kernel(
    const float* __restrict__ x,
    const int* __restrict__ indices,
    const float* __restrict__ weight,
    float* __restrict__ out)
{
    // 4 rows * 1152 floats = 18 KB -> 8 blocks/CU = 32 waves/CU.
    // Each WAVE owns one row: stages it and reads back only its own writes,
    // so no block-wide __syncthreads is needed (DS ops in-order per wave).
    __shared__ float lds_x[ROWS_PER_BLOCK * MUL * IRREP];

    const int t    = threadIdx.x;
    const int wave = t >> 6;
    const int lane = t & 63;
    const int block_row0 = blockIdx.x * ROWS_PER_BLOCK;
    const int row_g = block_row0 + wave;           // global batch row for this wave

    // Stage this wave's row: 1152 floats = 288 float4; 4 per lane + 32 extra.
    const float4* gsrc = reinterpret_cast<const float4*>(x + (size_t)row_g * (MUL * IRREP));
    float4* ldst = reinterpret_cast<float4*>(&lds_x[wave * (MUL * IRREP)]);
#pragma unroll
    for (int j = 0; j < 4; ++j) {
        ldst[lane + j * 64] = gsrc[lane + j * 64];
    }
    if (lane < 32) {
        ldst[lane + 256] = gsrc[lane + 256];
    }
    // Wave-local "barrier": DS pipe is in-order per wave; wait for our own
    // ds_writes to commit, and stop the compiler reordering LDS ops across.
    asm volatile("s_waitcnt lgkmcnt(0)" ::: "memory");
    __builtin_amdgcn_wave_barrier();

    const float s2c = 0.70710678118654752440f;  // 1/sqrt(2)
    const float s6c = 0.40824829046386301637f;  // 1/sqrt(6)

    const int e = indices[row_g];  // wave-uniform -> scalar broadcast load

#pragma unroll
    for (int j = 0; j < 2; ++j) {
        const int m = lane + j * 64;               // 0..127

        const float* xp = &lds_x[wave * (MUL * IRREP) + m * IRREP];
        const float s  = xp[0];
        const float v0 = xp[1], v1 = xp[2], v2 = xp[3];
        const float q0 = xp[4], q1 = xp[5], q2 = xp[6], q3 = xp[7], q4 = xp[8];

        // Q = sum_a q[a] * B[a]; symmetric traceless 3x3, 6 unique entries
        const float Q00 = -s6c * q2 + s2c * q4;
        const float Q11 = -s6c * q2 - s2c * q4;
        const float Q22 = 2.0f * s6c * q2;
        const float Q01 = s2c * q0;
        const float Q12 = s2c * q1;
        const float Q02 = s2c * q3;

        const float vv = v0 * v0 + v1 * v1 + v2 * v2;
        const float qq = q0 * q0 + q1 * q1 + q2 * q2 + q3 * q3 + q4 * q4;

        const float vQv = v0 * v0 * Q00 + v1 * v1 * Q11 + v2 * v2 * Q22
                        + 2.0f * (v0 * v1 * Q01 + v1 * v2 * Q12 + v0 * v2 * Q02);

        // tr(Q^3) symmetric: a^3+b^3+c^3 + 3[d^2(a+b)+e^2(a+c)+f^2(b+c)] + 6def
        const float trQ3 = Q00 * Q00 * Q00 + Q11 * Q11 * Q11 + Q22 * Q22 * Q22
                         + 3.0f * (Q01 * Q01 * (Q00 + Q11)
                                 + Q02 * Q02 * (Q00 + Q22)
                                 + Q12 * Q12 * (Q11 + Q22))
                         + 6.0f * Q01 * Q02 * Q12;

        const float* wp = weight + (size_t)e * (IRREP * MUL) + m;

        const float ss = s * s;
        float acc = s         * wp[0 * MUL]
                  + ss        * wp[1 * MUL]
                  + vv        * wp[2 * MUL]
                  + qq        * wp[3 * MUL]
                  + (ss * s)  * wp[4 * MUL]
                  + (s * vv)  * wp[5 * MUL]
                  + (s * qq)  * wp[6 * MUL]
                  + vQv       * wp[7 * MUL]
                  + trQ3      * wp[8 * MUL];

        __builtin_nontemporal_store(acc, &out[(size_t)row_g * MUL + m]);
    }
}

extern "C" void kernel_launch(void* const* d_in, const int* in_sizes, int n_in,
                              void* d_out, int out_size, void* d_ws, size_t ws_size,
                              hipStream_t stream) {
    const float* x       = (const float*)d_in[0];
    const int*   indices = (const int*)d_in[1];
    const float* weight  = (const float*)d_in[2];
    float* out = (float*)d_out;

    const int blocks = BATCH / ROWS_PER_BLOCK;  // 32768
    symcon_kernel<<<blocks, THREADS, 0, stream>>>(x, indices, weight, out);
}

// Round 5
// 114.366 us; speedup vs baseline: 1.0200x; 1.0200x over previous
//
#include <hip/hip_runtime.h>

#define BATCH 131072
#define MUL 128
#define IRREP 9
#define ROWS_PER_BLOCK 4
#define THREADS 256
#define PAIRS_PER_THREAD 2   // ROWS_PER_BLOCK*MUL / THREADS

// Best-measured variant (R3, 115.0 us = 5.82 TB/s effective, 92.5% of the
// measured float4-copy ceiling). Structure: 18 KB LDS tile -> 8 blocks/CU =
// 32 waves/CU (occupancy-max); coalesced float4 staging; block barrier;
// stride-9 LDS reads (2-way bank aliasing = free); wave-uniform weight
// gather (L2-resident 294 KB table); nontemporal stores.
__global__ __launch_bounds__(THREADS, 8) void symcon_kernel(
    const float* __restrict__ x,
    const int* __restrict__ indices,
    const float* __restrict__ weight,
    float* __restrict__ out)
{
    __shared__ float lds_x[ROWS_PER_BLOCK * MUL * IRREP];

    const int t = threadIdx.x;
    const int block_row0 = blockIdx.x * ROWS_PER_BLOCK;

    // Stage 4 rows = 1152 float4 via coalesced 16B loads:
    // 4 per thread + one extra for the first 128 threads.
    const float4* gsrc = reinterpret_cast<const float4*>(x + (size_t)block_row0 * (MUL * IRREP));
    float4* ldst = reinterpret_cast<float4*>(lds_x);
#pragma unroll
    for (int j = 0; j < 4; ++j) {
        ldst[t + j * THREADS] = gsrc[t + j * THREADS];
    }
    if (t < 128) {
        ldst[t + 4 * THREADS] = gsrc[t + 4 * THREADS];
    }
    __syncthreads();

    const float s2c = 0.70710678118654752440f;  // 1/sqrt(2)
    const float s6c = 0.40824829046386301637f;  // 1/sqrt(6)

#pragma unroll
    for (int j = 0; j < PAIRS_PER_THREAD; ++j) {
        const int pair = t + j * THREADS;      // 0..511
        const int row  = pair >> 7;            // 0..3
        const int m    = pair & (MUL - 1);     // 0..127 (wave: same row, consecutive m)

        const float* xp = &lds_x[row * (MUL * IRREP) + m * IRREP];
        const float s  = xp[0];
        const float v0 = xp[1], v1 = xp[2], v2 = xp[3];
        const float q0 = xp[4], q1 = xp[5], q2 = xp[6], q3 = xp[7], q4 = xp[8];

        // Q = sum_a q[a] * B[a]; symmetric traceless 3x3, 6 unique entries
        const float Q00 = -s6c * q2 + s2c * q4;
        const float Q11 = -s6c * q2 - s2c * q4;
        const float Q22 = 2.0f * s6c * q2;
        const float Q01 = s2c * q0;
        const float Q12 = s2c * q1;
        const float Q02 = s2c * q3;

        const float vv = v0 * v0 + v1 * v1 + v2 * v2;
        const float qq = q0 * q0 + q1 * q1 + q2 * q2 + q3 * q3 + q4 * q4;

        const float vQv = v0 * v0 * Q00 + v1 * v1 * Q11 + v2 * v2 * Q22
                        + 2.0f * (v0 * v1 * Q01 + v1 * v2 * Q12 + v0 * v2 * Q02);

        // tr(Q^3) symmetric: a^3+b^3+c^3 + 3[d^2(a+b)+e^2(a+c)+f^2(b+c)] + 6def
        const float trQ3 = Q00 * Q00 * Q00 + Q11 * Q11 * Q11 + Q22 * Q22 * Q22
                         + 3.0f * (Q01 * Q01 * (Q00 + Q11)
                                 + Q02 * Q02 * (Q00 + Q22)
                                 + Q12 * Q12 * (Q11 + Q22))
                         + 6.0f * Q01 * Q02 * Q12;

        const int b = block_row0 + row;
        const int e = indices[b];  // wave-uniform -> broadcast
        const float* wp = weight + (size_t)e * (IRREP * MUL) + m;

        const float ss = s * s;
        float acc = s         * wp[0 * MUL]
                  + ss        * wp[1 * MUL]
                  + vv        * wp[2 * MUL]
                  + qq        * wp[3 * MUL]
                  + (ss * s)  * wp[4 * MUL]
                  + (s * vv)  * wp[5 * MUL]
                  + (s * qq)  * wp[6 * MUL]
                  + vQv       * wp[7 * MUL]
                  + trQ3      * wp[8 * MUL];

        __builtin_nontemporal_store(acc, &out[(size_t)b * MUL + m]);
    }
}

extern "C" void kernel_launch(void* const* d_in, const int* in_sizes, int n_in,
                              void* d_out, int out_size, void* d_ws, size_t ws_size,
                              hipStream_t stream) {
    const float* x       = (const float*)d_in[0];
    const int*   indices = (const int*)d_in[1];
    const float* weight  = (const float*)d_in[2];
    float* out = (float*)d_out;

    const int blocks = BATCH / ROWS_PER_BLOCK;  // 32768
    symcon_kernel<<<blocks, THREADS, 0, stream>>>(x, indices, weight, out);
}